// Round 3
// baseline (3908.683 us; speedup 1.0000x reference)
//
#include <hip/hip_runtime.h>
#include <stdint.h>

#define NN 100000   // nodes
#define NE 400000   // edges before self loops
#define NT 500000   // NE + NN
#define DA 98       // atom feature dim
#define DB 13       // bond feature dim
#define EMB 128
#define HE 512      // HEADS * EMB

__device__ __forceinline__ float prelu_f(float x, float a) { return x >= 0.f ? x : a * x; }

// bf16 <-> fp32 helpers (bf16 stored as unsigned short)
__device__ __forceinline__ unsigned short f2bf(float f) {
    unsigned u = __float_as_uint(f);
    unsigned r = (u + 0x7fffu + ((u >> 16) & 1u)) >> 16;  // round-to-nearest-even
    return (unsigned short)r;
}
__device__ __forceinline__ float bflo(unsigned u) { return __uint_as_float(u << 16); }
__device__ __forceinline__ float bfhi(unsigned u) { return __uint_as_float(u & 0xffff0000u); }

// ----------------- CSR build -----------------
// edge_index is INT32 on device (JAX x64 disabled; harness: integer -> const int*)
__global__ void k_count(const int* __restrict__ ei, int* __restrict__ sc, int* __restrict__ dc) {
    int e = blockIdx.x * 256 + threadIdx.x;
    if (e >= NT) return;
    int s, d;
    if (e < NE) { s = ei[e]; d = ei[NE + e]; } else { s = d = e - NE; }
    atomicAdd(sc + s, 1);
    atomicAdd(dc + d, 1);
}

__global__ void k_scan1(const int* __restrict__ cnt, int* __restrict__ part, int* __restrict__ bsum) {
    __shared__ int tmp[512];
    int t = threadIdx.x, i = blockIdx.x * 512 + t;
    int v = (i < NN) ? cnt[i] : 0;
    tmp[t] = v;
    __syncthreads();
    for (int off = 1; off < 512; off <<= 1) {
        int x = (t >= off) ? tmp[t - off] : 0;
        __syncthreads();
        tmp[t] += x;
        __syncthreads();
    }
    if (i < NN) part[i] = tmp[t] - v;   // exclusive within block
    if (t == 511) bsum[blockIdx.x] = tmp[t];
}

__global__ void k_scan2(int* __restrict__ bsum, int nb) {
    __shared__ int tmp[256];
    int t = threadIdx.x;
    int v = (t < nb) ? bsum[t] : 0;
    tmp[t] = v;
    __syncthreads();
    for (int off = 1; off < 256; off <<= 1) {
        int x = (t >= off) ? tmp[t - off] : 0;
        __syncthreads();
        tmp[t] += x;
        __syncthreads();
    }
    if (t < nb) bsum[t] = tmp[t] - v;   // exclusive
}

__global__ void k_scan3(const int* __restrict__ part, const int* __restrict__ bsum,
                        int* __restrict__ off, int* __restrict__ cur) {
    int i = blockIdx.x * 256 + threadIdx.x;
    if (i < NN) {
        int v = part[i] + bsum[i >> 9];
        off[i] = v;
        cur[i] = v;
    }
    if (i == 0) off[NN] = NT;
}

__global__ void k_fill(const int* __restrict__ ei, int* __restrict__ scur, int* __restrict__ dcur,
                       int* __restrict__ seid, int* __restrict__ deid) {
    int e = blockIdx.x * 256 + threadIdx.x;
    if (e >= NT) return;
    int s, d;
    if (e < NE) { s = ei[e]; d = ei[NE + e]; } else { s = d = e - NE; }
    seid[atomicAdd(scur + s, 1)] = e;
    deid[atomicAdd(dcur + d, 1)] = e;
}

// ----------------- input embedding: h = prelu(x @ x_emb_W) -----------------
__global__ __launch_bounds__(128) void k_embed(const float* __restrict__ x, const float* __restrict__ W,
                                               const float* __restrict__ pg, float* __restrict__ h) {
    __shared__ float Ws[DA * EMB];   // 50 KB
    __shared__ float xr[DA];
    int t = threadIdx.x;
    for (int i = t; i < DA * EMB; i += 128) Ws[i] = W[i];
    float p = pg[0];
    __syncthreads();
    for (int n = blockIdx.x; n < NN; n += gridDim.x) {
        if (t < DA) xr[t] = x[(size_t)n * DA + t];
        __syncthreads();
        float acc = 0.f;
        #pragma unroll
        for (int k = 0; k < DA; ++k) acc += xr[k] * Ws[k * EMB + t];
        h[(size_t)n * EMB + t] = prelu_f(acc, p);
        __syncthreads();
    }
}

// ----------------- per-layer GEMM: xw = prelu(h @ Wl + bl), bf16 output ------
// 32 rows x 128 cols per block, 256 threads, 4x4 register tile.
// W tile staged in two 64x128 K-halves so LDS = 32+16 = 48 KB (< 64 KB limit).
__global__ __launch_bounds__(256) void k_gemm(const float* __restrict__ h, const float* __restrict__ Wl,
                                              const float* __restrict__ bl, const float* __restrict__ pa,
                                              unsigned short* __restrict__ xw) {
    __shared__ __align__(16) float Wc[64 * 128];   // 32 KB
    __shared__ __align__(16) float hT[32 * 128];   // 16 KB
    int t = threadIdx.x;
    int row0 = blockIdx.x * 32;
    int chunk = blockIdx.y;   // 0..3: which 128-col slab of the 512
    for (int i = t; i < 32 * 128; i += 256)
        hT[i] = h[(size_t)(row0 + (i >> 7)) * EMB + (i & 127)];
    float a = pa[0];
    int cb = t & 31, rb = t >> 5;  // this thread: cols cb*4+jj, rows rb+8*i
    float acc[4][4] = {};
    for (int half = 0; half < 2; ++half) {
        __syncthreads();
        for (int i = t; i < 64 * 128; i += 256)
            Wc[i] = Wl[(size_t)(half * 64 + (i >> 7)) * HE + chunk * 128 + (i & 127)];
        __syncthreads();
        #pragma unroll 4
        for (int k4 = 0; k4 < 16; ++k4) {
            float4 hv4[4], wv4[4];
            #pragma unroll
            for (int i = 0; i < 4; ++i)
                hv4[i] = *(const float4*)&hT[(rb + 8 * i) * 128 + half * 64 + k4 * 4];
            #pragma unroll
            for (int kk = 0; kk < 4; ++kk)
                wv4[kk] = *(const float4*)&Wc[(k4 * 4 + kk) * 128 + cb * 4];
            #pragma unroll
            for (int i = 0; i < 4; ++i) {
                float hv[4] = {hv4[i].x, hv4[i].y, hv4[i].z, hv4[i].w};
                #pragma unroll
                for (int kk = 0; kk < 4; ++kk) {
                    const float* wv = (const float*)&wv4[kk];
                    acc[i][0] += hv[kk] * wv[0];
                    acc[i][1] += hv[kk] * wv[1];
                    acc[i][2] += hv[kk] * wv[2];
                    acc[i][3] += hv[kk] * wv[3];
                }
            }
        }
    }
    #pragma unroll
    for (int i = 0; i < 4; ++i) {
        int n = row0 + rb + 8 * i;
        int c = chunk * 128 + cb * 4;
        ushort4 o;
        o.x = f2bf(prelu_f(acc[i][0] + bl[c + 0], a));
        o.y = f2bf(prelu_f(acc[i][1] + bl[c + 1], a));
        o.z = f2bf(prelu_f(acc[i][2] + bl[c + 2], a));
        o.w = f2bf(prelu_f(acc[i][3] + bl[c + 3], a));
        *(ushort4*)&xw[(size_t)n * HE + c] = o;
    }
}

// ----------------- per-node attention dots: ddst = xw.att1, dsrc = xw.att2 ----
__global__ __launch_bounds__(256) void k_dots(const unsigned short* __restrict__ xw,
                                              const float* __restrict__ attl,
                                              float* __restrict__ ddst, float* __restrict__ dsrc) {
    int t = threadIdx.x;
    int lane = t & 63;
    int wid = blockIdx.x * 4 + (t >> 6);
    int nw = gridDim.x * 4;
    int hd = lane >> 4;
    int cm = (lane & 15) * 8;
    float a1[8], a2[8];
    #pragma unroll
    for (int q = 0; q < 8; ++q) {
        a1[q] = attl[hd * 256 + cm + q];
        a2[q] = attl[hd * 256 + 128 + cm + q];
    }
    for (int n = wid; n < NN; n += nw) {
        uint4 u = *(const uint4*)&xw[(size_t)n * HE + lane * 8];
        float v[8] = {bflo(u.x), bfhi(u.x), bflo(u.y), bfhi(u.y),
                      bflo(u.z), bfhi(u.z), bflo(u.w), bfhi(u.w)};
        float p1 = 0.f, p2 = 0.f;
        #pragma unroll
        for (int q = 0; q < 8; ++q) { p1 += v[q] * a1[q]; p2 += v[q] * a2[q]; }
        #pragma unroll
        for (int m = 1; m < 16; m <<= 1) {
            p1 += __shfl_xor(p1, m, 64);
            p2 += __shfl_xor(p2, m, 64);
        }
        if ((lane & 15) == 0) {
            ddst[n * 4 + hd] = p1;
            dsrc[n * 4 + hd] = p2;
        }
    }
}

// ----------------- per-edge raw attention logits (wave per edge) -----------------
__global__ __launch_bounds__(256) void k_edge(const int* __restrict__ ei, const float* __restrict__ ea,
                                              const float* __restrict__ eWl, const float* __restrict__ ebl,
                                              const float* __restrict__ attl, const float* __restrict__ pa,
                                              const float* __restrict__ ddst, const float* __restrict__ dsrc,
                                              float* __restrict__ alpha) {
    __shared__ __align__(16) float Ws[DB * HE];  // 26 KB
    int t = threadIdx.x;
    for (int i = t; i < DB * HE; i += 256) Ws[i] = eWl[i];
    float a = pa[0];
    int lane = t & 63;
    int wid = blockIdx.x * 4 + (t >> 6);
    int nw = gridDim.x * 4;
    int hd = lane >> 4;
    int cm = (lane & 15) * 8;
    int c0 = lane * 8;
    float a2[8], eb[8];
    #pragma unroll
    for (int q = 0; q < 8; ++q) {
        a2[q] = attl[hd * 256 + 128 + cm + q];
        eb[q] = ebl[c0 + q];
    }
    float pself = 0.f;  // self-loop edges: ea = 0 => ee = prelu(eb)
    #pragma unroll
    for (int q = 0; q < 8; ++q) pself += prelu_f(eb[q], a) * a2[q];
    __syncthreads();
    for (int e = wid; e < NT; e += nw) {
        int s, d;
        float p;
        if (e < NE) {
            s = ei[e]; d = ei[NE + e];
            float eav[DB];
            #pragma unroll
            for (int k = 0; k < DB; ++k) eav[k] = ea[(size_t)e * DB + k];
            float v[8];
            #pragma unroll
            for (int q = 0; q < 8; ++q) v[q] = eb[q];
            #pragma unroll
            for (int k = 0; k < DB; ++k) {
                float4 w0 = *(const float4*)&Ws[k * HE + c0];
                float4 w1 = *(const float4*)&Ws[k * HE + c0 + 4];
                v[0] += eav[k] * w0.x; v[1] += eav[k] * w0.y;
                v[2] += eav[k] * w0.z; v[3] += eav[k] * w0.w;
                v[4] += eav[k] * w1.x; v[5] += eav[k] * w1.y;
                v[6] += eav[k] * w1.z; v[7] += eav[k] * w1.w;
            }
            p = 0.f;
            #pragma unroll
            for (int q = 0; q < 8; ++q) p += prelu_f(v[q], a) * a2[q];
        } else {
            s = d = e - NE;
            p = pself;
        }
        #pragma unroll
        for (int m = 1; m < 16; m <<= 1) p += __shfl_xor(p, m, 64);
        if ((lane & 15) == 0) {
            float di = ddst[d * 4 + hd];
            float sj = dsrc[s * 4 + hd];
            alpha[e * 4 + hd] = prelu_f(di + sj + p, a);
        }
    }
}

// ----------------- segment softmax over src groups (thread per node) ---------
__global__ void k_softmax(const int* __restrict__ soff, const int* __restrict__ seid,
                          float4* __restrict__ alpha) {
    int n = blockIdx.x * 256 + threadIdx.x;
    if (n >= NN) return;
    int b = soff[n], e = soff[n + 1];
    float mx = -1e30f, my = -1e30f, mz = -1e30f, mw = -1e30f;
    for (int i = b; i < e; ++i) {
        float4 v = alpha[seid[i]];
        mx = fmaxf(mx, v.x); my = fmaxf(my, v.y);
        mz = fmaxf(mz, v.z); mw = fmaxf(mw, v.w);
    }
    float sx = 0.f, sy = 0.f, sz = 0.f, sw = 0.f;
    for (int i = b; i < e; ++i) {
        int id = seid[i];
        float4 v = alpha[id];
        v.x = __expf(v.x - mx); v.y = __expf(v.y - my);
        v.z = __expf(v.z - mz); v.w = __expf(v.w - mw);
        sx += v.x; sy += v.y; sz += v.z; sw += v.w;
        alpha[id] = v;
    }
    sx = 1.f / (sx + 1e-16f); sy = 1.f / (sy + 1e-16f);
    sz = 1.f / (sz + 1e-16f); sw = 1.f / (sw + 1e-16f);
    for (int i = b; i < e; ++i) {
        int id = seid[i];
        float4 v = alpha[id];
        v.x *= sx; v.y *= sy; v.z *= sz; v.w *= sw;
        alpha[id] = v;
    }
}

// ----------------- aggregation + head-mean + bias + LayerNorm (+PReLU) -------
__global__ __launch_bounds__(256) void k_aggr(const int* __restrict__ ei, const float* __restrict__ ea,
                                              const float* __restrict__ eWl, const float* __restrict__ ebl,
                                              const float* __restrict__ pa, const unsigned short* __restrict__ xw,
                                              const float* __restrict__ alpha,
                                              const int* __restrict__ doff, const int* __restrict__ deid,
                                              const float* __restrict__ gbias, const float* __restrict__ lng,
                                              const float* __restrict__ lnb, const float* __restrict__ pgnn,
                                              int last, float* __restrict__ hout) {
    __shared__ __align__(16) float Ws[DB * HE];  // 26 KB
    int t = threadIdx.x;
    for (int i = t; i < DB * HE; i += 256) Ws[i] = eWl[i];
    float a = pa[0], pg = pgnn[0];
    int lane = t & 63;
    int wid = blockIdx.x * 4 + (t >> 6);
    int nw = gridDim.x * 4;
    int hd = lane >> 4;
    int cm = (lane & 15) * 8;
    int c0 = lane * 8;
    float eb[8], ebp[8], gb[8], g[8], bb[8];
    #pragma unroll
    for (int q = 0; q < 8; ++q) {
        eb[q] = ebl[c0 + q];
        ebp[q] = prelu_f(eb[q], a);
        gb[q] = gbias[cm + q];
        g[q] = lng[cm + q];
        bb[q] = lnb[cm + q];
    }
    __syncthreads();
    for (int n = wid; n < NN; n += nw) {
        float acc[8] = {0.f, 0.f, 0.f, 0.f, 0.f, 0.f, 0.f, 0.f};
        int b0 = doff[n], b1 = doff[n + 1];
        for (int i = b0; i < b1; ++i) {
            int eid = deid[i];
            float4 al4 = *(const float4*)&alpha[eid * 4];
            float alv = hd == 0 ? al4.x : hd == 1 ? al4.y : hd == 2 ? al4.z : al4.w;
            int s;
            float wv[8];
            if (eid < NE) {
                s = ei[eid];
                float eav[DB];
                #pragma unroll
                for (int k = 0; k < DB; ++k) eav[k] = ea[(size_t)eid * DB + k];
                #pragma unroll
                for (int q = 0; q < 8; ++q) wv[q] = eb[q];
                #pragma unroll
                for (int k = 0; k < DB; ++k) {
                    float4 w0 = *(const float4*)&Ws[k * HE + c0];
                    float4 w1 = *(const float4*)&Ws[k * HE + c0 + 4];
                    wv[0] += eav[k] * w0.x; wv[1] += eav[k] * w0.y;
                    wv[2] += eav[k] * w0.z; wv[3] += eav[k] * w0.w;
                    wv[4] += eav[k] * w1.x; wv[5] += eav[k] * w1.y;
                    wv[6] += eav[k] * w1.z; wv[7] += eav[k] * w1.w;
                }
                #pragma unroll
                for (int q = 0; q < 8; ++q) wv[q] = prelu_f(wv[q], a);
            } else {
                s = eid - NE;
                #pragma unroll
                for (int q = 0; q < 8; ++q) wv[q] = ebp[q];
            }
            uint4 u = *(const uint4*)&xw[(size_t)s * HE + c0];
            float xv[8] = {bflo(u.x), bfhi(u.x), bflo(u.y), bfhi(u.y),
                           bflo(u.z), bfhi(u.z), bflo(u.w), bfhi(u.w)};
            #pragma unroll
            for (int q = 0; q < 8; ++q) acc[q] += (xv[q] + wv[q]) * alv;
        }
        // mean over heads: combine lanes {L, L+16, L+32, L+48}
        float hm[8];
        #pragma unroll
        for (int q = 0; q < 8; ++q) {
            float v = acc[q];
            v += __shfl_xor(v, 16, 64);
            v += __shfl_xor(v, 32, 64);
            hm[q] = 0.25f * v + gb[q];
        }
        // LayerNorm over 128 (each 16-lane group holds a full replica)
        float s8 = 0.f, q8 = 0.f;
        #pragma unroll
        for (int q = 0; q < 8; ++q) { s8 += hm[q]; q8 += hm[q] * hm[q]; }
        #pragma unroll
        for (int m = 1; m < 16; m <<= 1) {
            s8 += __shfl_xor(s8, m, 64);
            q8 += __shfl_xor(q8, m, 64);
        }
        float mu = s8 * (1.f / 128.f);
        float var = q8 * (1.f / 128.f) - mu * mu;
        float rstd = rsqrtf(var + 1e-5f);
        if (lane < 16) {
            float o[8];
            #pragma unroll
            for (int q = 0; q < 8; ++q) {
                float v = (hm[q] - mu) * rstd * g[q] + bb[q];
                o[q] = last ? v : prelu_f(v, pg);
            }
            float4* op = (float4*)&hout[(size_t)n * EMB + lane * 8];
            op[0] = make_float4(o[0], o[1], o[2], o[3]);
            op[1] = make_float4(o[4], o[5], o[6], o[7]);
        }
    }
}

extern "C" void kernel_launch(void* const* d_in, const int* in_sizes, int n_in,
                              void* d_out, int out_size, void* d_ws, size_t ws_size,
                              hipStream_t stream) {
    const float* x     = (const float*)d_in[0];
    const int*   ei    = (const int*)d_in[1];      // int32! (JAX x64 disabled)
    const float* ea    = (const float*)d_in[2];
    const float* xembW = (const float*)d_in[3];
    const float* pgnn  = (const float*)d_in[4];
    const float* wlW   = (const float*)d_in[5];
    const float* wlb   = (const float*)d_in[6];
    const float* att   = (const float*)d_in[7];
    const float* gbias = (const float*)d_in[8];
    const float* eeW   = (const float*)d_in[9];
    const float* eeb   = (const float*)d_in[10];
    const float* pgat  = (const float*)d_in[11];
    const float* lng   = (const float*)d_in[12];
    const float* lnb   = (const float*)d_in[13];

    char* w = (char*)d_ws;
    size_t off = 0;
    auto alloc = [&](size_t nbytes) -> char* {
        char* p = w + off;
        off += (nbytes + 255) & ~(size_t)255;
        return p;
    };
    float*          h     = (float*)alloc((size_t)NN * EMB * 4);          // 51.2 MB
    unsigned short* xw    = (unsigned short*)alloc((size_t)NN * HE * 2);  // 102.4 MB (bf16)
    float*          ddst  = (float*)alloc((size_t)NN * 4 * 4);
    float*          dsrc  = (float*)alloc((size_t)NN * 4 * 4);
    float*          alpha = (float*)alloc((size_t)NT * 4 * 4);            // 8 MB
    int* scnt = (int*)alloc((size_t)NN * 4);
    int* dcnt = (int*)alloc((size_t)NN * 4);
    int* soff = (int*)alloc((size_t)(NN + 1) * 4);
    int* doff = (int*)alloc((size_t)(NN + 1) * 4);
    int* scur = (int*)alloc((size_t)NN * 4);
    int* dcur = (int*)alloc((size_t)NN * 4);
    int* seid = (int*)alloc((size_t)NT * 4);
    int* deid = (int*)alloc((size_t)NT * 4);
    int* part = (int*)alloc((size_t)NN * 4);
    int* bsum = (int*)alloc(256 * 4);

    hipMemsetAsync(scnt, 0, (size_t)NN * 4, stream);
    hipMemsetAsync(dcnt, 0, (size_t)NN * 4, stream);
    k_count<<<(NT + 255) / 256, 256, 0, stream>>>(ei, scnt, dcnt);
    k_scan1<<<196, 512, 0, stream>>>(scnt, part, bsum);
    k_scan2<<<1, 256, 0, stream>>>(bsum, 196);
    k_scan3<<<391, 256, 0, stream>>>(part, bsum, soff, scur);
    k_scan1<<<196, 512, 0, stream>>>(dcnt, part, bsum);
    k_scan2<<<1, 256, 0, stream>>>(bsum, 196);
    k_scan3<<<391, 256, 0, stream>>>(part, bsum, doff, dcur);
    k_fill<<<(NT + 255) / 256, 256, 0, stream>>>(ei, scur, dcur, seid, deid);
    k_embed<<<2048, 128, 0, stream>>>(x, xembW, pgnn, h);

    for (int l = 0; l < 4; ++l) {
        const float* Wl  = wlW + (size_t)l * EMB * HE;
        const float* bl  = wlb + (size_t)l * HE;
        const float* al  = att + (size_t)l * 1024;
        const float* eWl = eeW + (size_t)l * DB * HE;
        const float* ebl = eeb + (size_t)l * HE;
        const float* pa  = pgat + l;
        k_gemm<<<dim3(3125, 4), 256, 0, stream>>>(h, Wl, bl, pa, xw);
        k_dots<<<2048, 256, 0, stream>>>(xw, al, ddst, dsrc);
        k_edge<<<2048, 256, 0, stream>>>(ei, ea, eWl, ebl, al, pa, ddst, dsrc, alpha);
        k_softmax<<<391, 256, 0, stream>>>(soff, seid, (float4*)alpha);
        float* hout = (l == 3) ? (float*)d_out : h;
        k_aggr<<<2048, 256, 0, stream>>>(ei, ea, eWl, ebl, pa, xw, alpha, doff, deid,
                                         gbias + (size_t)l * EMB, lng + (size_t)l * EMB,
                                         lnb + (size_t)l * EMB, pgnn, (l == 3) ? 1 : 0, hout);
    }
}

// Round 4
// 3084.526 us; speedup vs baseline: 1.2672x; 1.2672x over previous
//
#include <hip/hip_runtime.h>
#include <stdint.h>

#define NN 100000   // nodes
#define NE 400000   // edges before self loops
#define NT 500000   // NE + NN
#define DA 98       // atom feature dim
#define DB 13       // bond feature dim
#define EMB 128
#define HE 512      // HEADS * EMB

typedef unsigned short ushort_t;
typedef __bf16 bf16x8 __attribute__((ext_vector_type(8)));
typedef float floatx4 __attribute__((ext_vector_type(4)));

__device__ __forceinline__ float prelu_f(float x, float a) { return x >= 0.f ? x : a * x; }

__device__ __forceinline__ ushort_t f2bf(float f) {
    unsigned u = __float_as_uint(f);
    unsigned r = (u + 0x7fffu + ((u >> 16) & 1u)) >> 16;  // RNE
    return (ushort_t)r;
}
__device__ __forceinline__ float bflo(unsigned u) { return __uint_as_float(u << 16); }
__device__ __forceinline__ float bfhi(unsigned u) { return __uint_as_float(u & 0xffff0000u); }

// ----------------- CSR build (edge_index is int32) -----------------
__global__ void k_count(const int* __restrict__ ei, int* __restrict__ sc, int* __restrict__ dc) {
    int e = blockIdx.x * 256 + threadIdx.x;
    if (e >= NT) return;
    int s, d;
    if (e < NE) { s = ei[e]; d = ei[NE + e]; } else { s = d = e - NE; }
    atomicAdd(sc + s, 1);
    atomicAdd(dc + d, 1);
}

__global__ void k_scan1(const int* __restrict__ cnt, int* __restrict__ part, int* __restrict__ bsum) {
    __shared__ int tmp[512];
    int t = threadIdx.x, i = blockIdx.x * 512 + t;
    int v = (i < NN) ? cnt[i] : 0;
    tmp[t] = v;
    __syncthreads();
    for (int off = 1; off < 512; off <<= 1) {
        int x = (t >= off) ? tmp[t - off] : 0;
        __syncthreads();
        tmp[t] += x;
        __syncthreads();
    }
    if (i < NN) part[i] = tmp[t] - v;
    if (t == 511) bsum[blockIdx.x] = tmp[t];
}

__global__ void k_scan2(int* __restrict__ bsum, int nb) {
    __shared__ int tmp[256];
    int t = threadIdx.x;
    int v = (t < nb) ? bsum[t] : 0;
    tmp[t] = v;
    __syncthreads();
    for (int off = 1; off < 256; off <<= 1) {
        int x = (t >= off) ? tmp[t - off] : 0;
        __syncthreads();
        tmp[t] += x;
        __syncthreads();
    }
    if (t < nb) bsum[t] = tmp[t] - v;
}

__global__ void k_scan3(const int* __restrict__ part, const int* __restrict__ bsum,
                        int* __restrict__ off, int* __restrict__ cur) {
    int i = blockIdx.x * 256 + threadIdx.x;
    if (i < NN) {
        int v = part[i] + bsum[i >> 9];
        off[i] = v;
        cur[i] = v;
    }
    if (i == 0) off[NN] = NT;
}

__global__ void k_fill(const int* __restrict__ ei, int* __restrict__ scur, int* __restrict__ dcur,
                       int* __restrict__ seid, int* __restrict__ deid) {
    int e = blockIdx.x * 256 + threadIdx.x;
    if (e >= NT) return;
    int s, d;
    if (e < NE) { s = ei[e]; d = ei[NE + e]; } else { s = d = e - NE; }
    seid[atomicAdd(scur + s, 1)] = e;
    deid[atomicAdd(dcur + d, 1)] = e;
}

// ----------------- input embedding: h(bf16) = prelu(x @ x_emb_W) -------------
__global__ __launch_bounds__(128) void k_embed(const float* __restrict__ x, const float* __restrict__ W,
                                               const float* __restrict__ pg, ushort_t* __restrict__ hb) {
    __shared__ float Ws[DA * EMB];   // 50 KB
    __shared__ float xr[DA];
    int t = threadIdx.x;
    for (int i = t; i < DA * EMB; i += 128) Ws[i] = W[i];
    float p = pg[0];
    __syncthreads();
    for (int n = blockIdx.x; n < NN; n += gridDim.x) {
        if (t < DA) xr[t] = x[(size_t)n * DA + t];
        __syncthreads();
        float acc = 0.f;
        #pragma unroll
        for (int k = 0; k < DA; ++k) acc += xr[k] * Ws[k * EMB + t];
        hb[(size_t)n * EMB + t] = f2bf(prelu_f(acc, p));
        __syncthreads();
    }
}

// ----------------- W prep: Wtg[l][n][k] bf16 = wl_W[l][k][n] -----------------
__global__ void k_prep(const float* __restrict__ wlW, ushort_t* __restrict__ Wtg) {
    int idx = blockIdx.x * 256 + threadIdx.x;   // 4*512*128
    if (idx >= 4 * 512 * 128) return;
    int k = idx & 127;
    int n = (idx >> 7) & 511;
    int l = idx >> 16;
    Wtg[idx] = f2bf(wlW[(size_t)l * 65536 + k * 512 + n]);
}

// ----------------- per-layer GEMM via MFMA: xw = prelu(h @ Wl + bl) ----------
// block: 256 thr (4 waves), tile M=64 x N=128, K=128. LDS 52.2 KB.
__global__ __launch_bounds__(256) void k_gemm(const ushort_t* __restrict__ hb, const ushort_t* __restrict__ Wtg,
                                              const float* __restrict__ bl, const float* __restrict__ pa,
                                              ushort_t* __restrict__ xw) {
    __shared__ ushort_t At[64 * 136];    // 17.4 KB, row pad 136 (conflict-free)
    __shared__ ushort_t Bt[128 * 136];   // 34.8 KB, Bt[n][k]
    int t = threadIdx.x;
    int m0 = blockIdx.x * 64;
    int n0 = blockIdx.y * 128;
    // stage A (h rows, bf16, uint4 = 8 elems)
    for (int idx = t; idx < 64 * 16; idx += 256) {
        int r = idx >> 4, co = (idx & 15) * 8;
        int gr = m0 + r; if (gr >= NN) gr = 0;
        *(uint4*)&At[r * 136 + co] = *(const uint4*)&hb[(size_t)gr * EMB + co];
    }
    // stage B from pre-transposed bf16 weights
    for (int idx = t; idx < 128 * 16; idx += 256) {
        int n = idx >> 4, ko = (idx & 15) * 8;
        *(uint4*)&Bt[n * 136 + ko] = *(const uint4*)&Wtg[(size_t)(n0 + n) * 128 + ko];
    }
    float a = pa[0];
    __syncthreads();

    int wv = t >> 6, lane = t & 63;
    int ml = lane & 15, kq = lane >> 4;
    int n0w = wv * 32;
    floatx4 acc[4][2];
    #pragma unroll
    for (int mt = 0; mt < 4; ++mt)
        #pragma unroll
        for (int nt = 0; nt < 2; ++nt)
            acc[mt][nt] = (floatx4){0.f, 0.f, 0.f, 0.f};

    #pragma unroll
    for (int k0 = 0; k0 < 128; k0 += 32) {
        bf16x8 af[4], bfv[2];
        #pragma unroll
        for (int mt = 0; mt < 4; ++mt) {
            uint4 u = *(const uint4*)&At[(mt * 16 + ml) * 136 + k0 + kq * 8];
            af[mt] = __builtin_bit_cast(bf16x8, u);
        }
        #pragma unroll
        for (int nt = 0; nt < 2; ++nt) {
            uint4 u = *(const uint4*)&Bt[(n0w + nt * 16 + ml) * 136 + k0 + kq * 8];
            bfv[nt] = __builtin_bit_cast(bf16x8, u);
        }
        #pragma unroll
        for (int mt = 0; mt < 4; ++mt)
            #pragma unroll
            for (int nt = 0; nt < 2; ++nt)
                acc[mt][nt] = __builtin_amdgcn_mfma_f32_16x16x32_bf16(af[mt], bfv[nt], acc[mt][nt], 0, 0, 0);
    }
    // epilogue: C/D layout col=lane&15, row=kq*4+q
    #pragma unroll
    for (int nt = 0; nt < 2; ++nt) {
        int col = n0 + n0w + nt * 16 + ml;
        float bv = bl[col];
        #pragma unroll
        for (int mt = 0; mt < 4; ++mt) {
            int row = m0 + mt * 16 + kq * 4;
            #pragma unroll
            for (int q = 0; q < 4; ++q) {
                int r = row + q;
                if (r < NN) xw[(size_t)r * HE + col] = f2bf(prelu_f(acc[mt][nt][q] + bv, a));
            }
        }
    }
}

// ----------------- per-node attention dots -----------------------------------
__global__ __launch_bounds__(256) void k_dots(const ushort_t* __restrict__ xw,
                                              const float* __restrict__ attl,
                                              float* __restrict__ ddst, float* __restrict__ dsrc) {
    int t = threadIdx.x;
    int lane = t & 63;
    int wid = blockIdx.x * 4 + (t >> 6);
    int nw = gridDim.x * 4;
    int hd = lane >> 4;
    int cm = (lane & 15) * 8;
    float a1[8], a2[8];
    #pragma unroll
    for (int q = 0; q < 8; ++q) {
        a1[q] = attl[hd * 256 + cm + q];
        a2[q] = attl[hd * 256 + 128 + cm + q];
    }
    for (int n = wid; n < NN; n += nw) {
        uint4 u = *(const uint4*)&xw[(size_t)n * HE + lane * 8];
        float v[8] = {bflo(u.x), bfhi(u.x), bflo(u.y), bfhi(u.y),
                      bflo(u.z), bfhi(u.z), bflo(u.w), bfhi(u.w)};
        float p1 = 0.f, p2 = 0.f;
        #pragma unroll
        for (int q = 0; q < 8; ++q) { p1 += v[q] * a1[q]; p2 += v[q] * a2[q]; }
        #pragma unroll
        for (int m = 1; m < 16; m <<= 1) {
            p1 += __shfl_xor(p1, m, 64);
            p2 += __shfl_xor(p2, m, 64);
        }
        if ((lane & 15) == 0) {
            ddst[n * 4 + hd] = p1;
            dsrc[n * 4 + hd] = p2;
        }
    }
}

// interleaved Ws staging: chunk j -> pos (j&1)*64 + j/2 so lane reads are
// wave-contiguous (float offsets 4L and 256+4L) -> conflict-free
__device__ __forceinline__ void stage_ws(float* Ws, const float* __restrict__ eWl, int t) {
    for (int i = t; i < DB * HE; i += 256) {
        int k = i >> 9, c = i & 511;
        int j = c >> 2, pos = ((j & 1) << 6) + (j >> 1);
        Ws[(k << 9) + (pos << 2) + (c & 3)] = eWl[i];
    }
}

// ----------------- per-edge raw attention logits ------------------------------
__global__ __launch_bounds__(256) void k_edge(const int* __restrict__ ei, const float* __restrict__ ea,
                                              const float* __restrict__ eWl, const float* __restrict__ ebl,
                                              const float* __restrict__ attl, const float* __restrict__ pa,
                                              const float* __restrict__ ddst, const float* __restrict__ dsrc,
                                              float* __restrict__ alpha) {
    __shared__ __align__(16) float Ws[DB * HE];  // 26 KB
    int t = threadIdx.x;
    stage_ws(Ws, eWl, t);
    float a = pa[0];
    int lane = t & 63;
    int wid = blockIdx.x * 4 + (t >> 6);
    int nw = gridDim.x * 4;
    int hd = lane >> 4;
    int cm = (lane & 15) * 8;
    int c0 = lane * 8;
    float a2[8], eb[8];
    #pragma unroll
    for (int q = 0; q < 8; ++q) {
        a2[q] = attl[hd * 256 + 128 + cm + q];
        eb[q] = ebl[c0 + q];
    }
    float pself = 0.f;
    #pragma unroll
    for (int q = 0; q < 8; ++q) pself += prelu_f(eb[q], a) * a2[q];
    __syncthreads();
    for (int e = wid; e < NT; e += nw) {
        int s, d;
        float p;
        if (e < NE) {
            s = ei[e]; d = ei[NE + e];
            float eav[DB];
            #pragma unroll
            for (int k = 0; k < DB; ++k) eav[k] = ea[(size_t)e * DB + k];
            float v[8];
            #pragma unroll
            for (int q = 0; q < 8; ++q) v[q] = eb[q];
            #pragma unroll
            for (int k = 0; k < DB; ++k) {
                float4 w0 = *(const float4*)&Ws[(k << 9) + (lane << 2)];
                float4 w1 = *(const float4*)&Ws[(k << 9) + 256 + (lane << 2)];
                v[0] += eav[k] * w0.x; v[1] += eav[k] * w0.y;
                v[2] += eav[k] * w0.z; v[3] += eav[k] * w0.w;
                v[4] += eav[k] * w1.x; v[5] += eav[k] * w1.y;
                v[6] += eav[k] * w1.z; v[7] += eav[k] * w1.w;
            }
            p = 0.f;
            #pragma unroll
            for (int q = 0; q < 8; ++q) p += prelu_f(v[q], a) * a2[q];
        } else {
            s = d = e - NE;
            p = pself;
        }
        #pragma unroll
        for (int m = 1; m < 16; m <<= 1) p += __shfl_xor(p, m, 64);
        if ((lane & 15) == 0) {
            float di = ddst[d * 4 + hd];
            float sj = dsrc[s * 4 + hd];
            alpha[e * 4 + hd] = prelu_f(di + sj + p, a);
        }
    }
}

// ----------------- segment softmax over src groups ---------------------------
__global__ void k_softmax(const int* __restrict__ soff, const int* __restrict__ seid,
                          float4* __restrict__ alpha) {
    int n = blockIdx.x * 256 + threadIdx.x;
    if (n >= NN) return;
    int b = soff[n], e = soff[n + 1];
    float mx = -1e30f, my = -1e30f, mz = -1e30f, mw = -1e30f;
    for (int i = b; i < e; ++i) {
        float4 v = alpha[seid[i]];
        mx = fmaxf(mx, v.x); my = fmaxf(my, v.y);
        mz = fmaxf(mz, v.z); mw = fmaxf(mw, v.w);
    }
    float sx = 0.f, sy = 0.f, sz = 0.f, sw = 0.f;
    for (int i = b; i < e; ++i) {
        int id = seid[i];
        float4 v = alpha[id];
        v.x = __expf(v.x - mx); v.y = __expf(v.y - my);
        v.z = __expf(v.z - mz); v.w = __expf(v.w - mw);
        sx += v.x; sy += v.y; sz += v.z; sw += v.w;
        alpha[id] = v;
    }
    sx = 1.f / (sx + 1e-16f); sy = 1.f / (sy + 1e-16f);
    sz = 1.f / (sz + 1e-16f); sw = 1.f / (sw + 1e-16f);
    for (int i = b; i < e; ++i) {
        int id = seid[i];
        float4 v = alpha[id];
        v.x *= sx; v.y *= sy; v.z *= sz; v.w *= sw;
        alpha[id] = v;
    }
}

// ----------------- aggregation + head-mean + bias + LayerNorm (+PReLU) -------
// 2-stage software pipeline: edge i+1's loads issued before edge i's compute.
__global__ __launch_bounds__(256) void k_aggr(const int* __restrict__ ei, const float* __restrict__ ea,
                                              const float* __restrict__ eWl, const float* __restrict__ ebl,
                                              const float* __restrict__ pa, const ushort_t* __restrict__ xw,
                                              const float* __restrict__ alpha,
                                              const int* __restrict__ doff, const int* __restrict__ deid,
                                              const float* __restrict__ gbias, const float* __restrict__ lng,
                                              const float* __restrict__ lnb, const float* __restrict__ pgnn,
                                              int last, ushort_t* __restrict__ hb_out, float* __restrict__ fout) {
    __shared__ __align__(16) float Ws[DB * HE];  // 26 KB
    int t = threadIdx.x;
    stage_ws(Ws, eWl, t);
    float a = pa[0], pg = pgnn[0];
    int lane = t & 63;
    int wid = blockIdx.x * 4 + (t >> 6);
    int nw = gridDim.x * 4;
    int hd = lane >> 4;
    int cm = (lane & 15) * 8;
    int c0 = lane * 8;
    float eb[8], ebp[8], gb[8], g[8], bb[8];
    #pragma unroll
    for (int q = 0; q < 8; ++q) {
        eb[q] = ebl[c0 + q];
        ebp[q] = prelu_f(eb[q], a);
        gb[q] = gbias[cm + q];
        g[q] = lng[cm + q];
        bb[q] = lnb[cm + q];
    }
    __syncthreads();
    for (int n = wid; n < NN; n += nw) {
        float acc[8] = {0.f, 0.f, 0.f, 0.f, 0.f, 0.f, 0.f, 0.f};
        int b0 = doff[n], b1 = doff[n + 1];
        // ---- prologue: load edge b0
        int eidA = deid[b0];
        float4 alA = *(const float4*)&alpha[eidA * 4];
        bool intA = eidA < NE;
        int sA;
        float eA[DB];
        if (intA) {
            sA = ei[eidA];
            #pragma unroll
            for (int k = 0; k < DB; ++k) eA[k] = ea[(size_t)eidA * DB + k];
        } else sA = eidA - NE;
        uint4 uA = *(const uint4*)&xw[(size_t)sA * HE + c0];
        for (int i = b0; i < b1; ++i) {
            // ---- prefetch edge i+1
            int eidB = 0, sB = 0;
            float4 alB = alA;
            bool intB = false, haveB = (i + 1 < b1);
            float eB[DB];
            uint4 uB = uA;
            if (haveB) {
                eidB = deid[i + 1];
                alB = *(const float4*)&alpha[eidB * 4];
                intB = eidB < NE;
                if (intB) {
                    sB = ei[eidB];
                    #pragma unroll
                    for (int k = 0; k < DB; ++k) eB[k] = ea[(size_t)eidB * DB + k];
                } else sB = eidB - NE;
                uB = *(const uint4*)&xw[(size_t)sB * HE + c0];
            }
            // ---- compute with edge A
            float alv = hd == 0 ? alA.x : hd == 1 ? alA.y : hd == 2 ? alA.z : alA.w;
            float wv[8];
            if (intA) {
                #pragma unroll
                for (int q = 0; q < 8; ++q) wv[q] = eb[q];
                #pragma unroll
                for (int k = 0; k < DB; ++k) {
                    float4 w0 = *(const float4*)&Ws[(k << 9) + (lane << 2)];
                    float4 w1 = *(const float4*)&Ws[(k << 9) + 256 + (lane << 2)];
                    wv[0] += eA[k] * w0.x; wv[1] += eA[k] * w0.y;
                    wv[2] += eA[k] * w0.z; wv[3] += eA[k] * w0.w;
                    wv[4] += eA[k] * w1.x; wv[5] += eA[k] * w1.y;
                    wv[6] += eA[k] * w1.z; wv[7] += eA[k] * w1.w;
                }
                #pragma unroll
                for (int q = 0; q < 8; ++q) wv[q] = prelu_f(wv[q], a);
            } else {
                #pragma unroll
                for (int q = 0; q < 8; ++q) wv[q] = ebp[q];
            }
            float xv[8] = {bflo(uA.x), bfhi(uA.x), bflo(uA.y), bfhi(uA.y),
                           bflo(uA.z), bfhi(uA.z), bflo(uA.w), bfhi(uA.w)};
            #pragma unroll
            for (int q = 0; q < 8; ++q) acc[q] += (xv[q] + wv[q]) * alv;
            // ---- rotate
            eidA = eidB; alA = alB; intA = intB; sA = sB; uA = uB;
            #pragma unroll
            for (int k = 0; k < DB; ++k) eA[k] = eB[k];
        }
        // mean over heads: combine lanes {L, L+16, L+32, L+48}
        float hm[8];
        #pragma unroll
        for (int q = 0; q < 8; ++q) {
            float v = acc[q];
            v += __shfl_xor(v, 16, 64);
            v += __shfl_xor(v, 32, 64);
            hm[q] = 0.25f * v + gb[q];
        }
        // LayerNorm over 128 (each 16-lane group holds a full replica)
        float s8 = 0.f, q8 = 0.f;
        #pragma unroll
        for (int q = 0; q < 8; ++q) { s8 += hm[q]; q8 += hm[q] * hm[q]; }
        #pragma unroll
        for (int m = 1; m < 16; m <<= 1) {
            s8 += __shfl_xor(s8, m, 64);
            q8 += __shfl_xor(q8, m, 64);
        }
        float mu = s8 * (1.f / 128.f);
        float var = q8 * (1.f / 128.f) - mu * mu;
        float rstd = rsqrtf(var + 1e-5f);
        if (lane < 16) {
            float o[8];
            #pragma unroll
            for (int q = 0; q < 8; ++q) {
                float v = (hm[q] - mu) * rstd * g[q] + bb[q];
                o[q] = last ? v : prelu_f(v, pg);
            }
            if (last) {
                float4* op = (float4*)&fout[(size_t)n * EMB + lane * 8];
                op[0] = make_float4(o[0], o[1], o[2], o[3]);
                op[1] = make_float4(o[4], o[5], o[6], o[7]);
            } else {
                uint4 ob;
                ob.x = (unsigned)f2bf(o[0]) | ((unsigned)f2bf(o[1]) << 16);
                ob.y = (unsigned)f2bf(o[2]) | ((unsigned)f2bf(o[3]) << 16);
                ob.z = (unsigned)f2bf(o[4]) | ((unsigned)f2bf(o[5]) << 16);
                ob.w = (unsigned)f2bf(o[6]) | ((unsigned)f2bf(o[7]) << 16);
                *(uint4*)&hb_out[(size_t)n * EMB + lane * 8] = ob;
            }
        }
    }
}

extern "C" void kernel_launch(void* const* d_in, const int* in_sizes, int n_in,
                              void* d_out, int out_size, void* d_ws, size_t ws_size,
                              hipStream_t stream) {
    const float* x     = (const float*)d_in[0];
    const int*   ei    = (const int*)d_in[1];      // int32 (JAX x64 disabled)
    const float* ea    = (const float*)d_in[2];
    const float* xembW = (const float*)d_in[3];
    const float* pgnn  = (const float*)d_in[4];
    const float* wlW   = (const float*)d_in[5];
    const float* wlb   = (const float*)d_in[6];
    const float* att   = (const float*)d_in[7];
    const float* gbias = (const float*)d_in[8];
    const float* eeW   = (const float*)d_in[9];
    const float* eeb   = (const float*)d_in[10];
    const float* pgat  = (const float*)d_in[11];
    const float* lng   = (const float*)d_in[12];
    const float* lnb   = (const float*)d_in[13];

    char* w = (char*)d_ws;
    size_t off = 0;
    auto alloc = [&](size_t nbytes) -> char* {
        char* p = w + off;
        off += (nbytes + 255) & ~(size_t)255;
        return p;
    };
    ushort_t* hb    = (ushort_t*)alloc((size_t)NN * EMB * 2);   // 25.6 MB bf16
    ushort_t* xw    = (ushort_t*)alloc((size_t)NN * HE * 2);    // 102.4 MB bf16
    ushort_t* Wtg   = (ushort_t*)alloc((size_t)4 * 512 * 128 * 2);
    float*    ddst  = (float*)alloc((size_t)NN * 4 * 4);
    float*    dsrc  = (float*)alloc((size_t)NN * 4 * 4);
    float*    alpha = (float*)alloc((size_t)NT * 4 * 4);        // 8 MB
    int* scnt = (int*)alloc((size_t)NN * 4);
    int* dcnt = (int*)alloc((size_t)NN * 4);
    int* soff = (int*)alloc((size_t)(NN + 1) * 4);
    int* doff = (int*)alloc((size_t)(NN + 1) * 4);
    int* scur = (int*)alloc((size_t)NN * 4);
    int* dcur = (int*)alloc((size_t)NN * 4);
    int* seid = (int*)alloc((size_t)NT * 4);
    int* deid = (int*)alloc((size_t)NT * 4);
    int* part = (int*)alloc((size_t)NN * 4);
    int* bsum = (int*)alloc(256 * 4);

    hipMemsetAsync(scnt, 0, (size_t)NN * 4, stream);
    hipMemsetAsync(dcnt, 0, (size_t)NN * 4, stream);
    k_count<<<(NT + 255) / 256, 256, 0, stream>>>(ei, scnt, dcnt);
    k_scan1<<<196, 512, 0, stream>>>(scnt, part, bsum);
    k_scan2<<<1, 256, 0, stream>>>(bsum, 196);
    k_scan3<<<391, 256, 0, stream>>>(part, bsum, soff, scur);
    k_scan1<<<196, 512, 0, stream>>>(dcnt, part, bsum);
    k_scan2<<<1, 256, 0, stream>>>(bsum, 196);
    k_scan3<<<391, 256, 0, stream>>>(part, bsum, doff, dcur);
    k_fill<<<(NT + 255) / 256, 256, 0, stream>>>(ei, scur, dcur, seid, deid);
    k_embed<<<2048, 128, 0, stream>>>(x, xembW, pgnn, hb);
    k_prep<<<(4 * 512 * 128 + 255) / 256, 256, 0, stream>>>(wlW, Wtg);

    for (int l = 0; l < 4; ++l) {
        const float* bl  = wlb + (size_t)l * HE;
        const float* al  = att + (size_t)l * 1024;
        const float* eWl = eeW + (size_t)l * DB * HE;
        const float* ebl = eeb + (size_t)l * HE;
        const float* pa  = pgat + l;
        const ushort_t* Wt = Wtg + (size_t)l * 512 * 128;
        k_gemm<<<dim3((NN + 63) / 64, 4), 256, 0, stream>>>(hb, Wt, bl, pa, xw);
        k_dots<<<2048, 256, 0, stream>>>(xw, al, ddst, dsrc);
        k_edge<<<2048, 256, 0, stream>>>(ei, ea, eWl, ebl, al, pa, ddst, dsrc, alpha);
        k_softmax<<<391, 256, 0, stream>>>(soff, seid, (float4*)alpha);
        k_aggr<<<2048, 256, 0, stream>>>(ei, ea, eWl, ebl, pa, xw, alpha, doff, deid,
                                         gbias + (size_t)l * EMB, lng + (size_t)l * EMB,
                                         lnb + (size_t)l * EMB, pgnn, (l == 3) ? 1 : 0,
                                         hb, (float*)d_out);
    }
}

// Round 5
// 3026.513 us; speedup vs baseline: 1.2915x; 1.0192x over previous
//
#include <hip/hip_runtime.h>
#include <stdint.h>

#define NN 100000   // nodes
#define NE 400000   // edges before self loops
#define NT 500000   // NE + NN
#define DA 98       // atom feature dim
#define DB 13       // bond feature dim
#define EMB 128
#define HE 512      // HEADS * EMB

typedef unsigned short ushort_t;
typedef __bf16 bf16x8 __attribute__((ext_vector_type(8)));
typedef float floatx4 __attribute__((ext_vector_type(4)));

__device__ __forceinline__ float prelu_f(float x, float a) { return x >= 0.f ? x : a * x; }

__device__ __forceinline__ ushort_t f2bf(float f) {
    unsigned u = __float_as_uint(f);
    unsigned r = (u + 0x7fffu + ((u >> 16) & 1u)) >> 16;  // RNE
    return (ushort_t)r;
}
__device__ __forceinline__ float bflo(unsigned u) { return __uint_as_float(u << 16); }
__device__ __forceinline__ float bfhi(unsigned u) { return __uint_as_float(u & 0xffff0000u); }

// ----------------- CSR build (edge_index is int32) -----------------
__global__ void k_count(const int* __restrict__ ei, int* __restrict__ sc, int* __restrict__ dc) {
    int e = blockIdx.x * 256 + threadIdx.x;
    if (e >= NT) return;
    int s, d;
    if (e < NE) { s = ei[e]; d = ei[NE + e]; } else { s = d = e - NE; }
    atomicAdd(sc + s, 1);
    atomicAdd(dc + d, 1);
}

__global__ void k_scan1(const int* __restrict__ cnt, int* __restrict__ part, int* __restrict__ bsum) {
    __shared__ int tmp[512];
    int t = threadIdx.x, i = blockIdx.x * 512 + t;
    int v = (i < NN) ? cnt[i] : 0;
    tmp[t] = v;
    __syncthreads();
    for (int off = 1; off < 512; off <<= 1) {
        int x = (t >= off) ? tmp[t - off] : 0;
        __syncthreads();
        tmp[t] += x;
        __syncthreads();
    }
    if (i < NN) part[i] = tmp[t] - v;
    if (t == 511) bsum[blockIdx.x] = tmp[t];
}

__global__ void k_scan2(int* __restrict__ bsum, int nb) {
    __shared__ int tmp[256];
    int t = threadIdx.x;
    int v = (t < nb) ? bsum[t] : 0;
    tmp[t] = v;
    __syncthreads();
    for (int off = 1; off < 256; off <<= 1) {
        int x = (t >= off) ? tmp[t - off] : 0;
        __syncthreads();
        tmp[t] += x;
        __syncthreads();
    }
    if (t < nb) bsum[t] = tmp[t] - v;
}

__global__ void k_scan3(const int* __restrict__ part, const int* __restrict__ bsum,
                        int* __restrict__ off, int* __restrict__ cur) {
    int i = blockIdx.x * 256 + threadIdx.x;
    if (i < NN) {
        int v = part[i] + bsum[i >> 9];
        off[i] = v;
        cur[i] = v;
    }
    if (i == 0) off[NN] = NT;
}

__global__ void k_fill(const int* __restrict__ ei, int* __restrict__ scur, int* __restrict__ dcur,
                       int* __restrict__ seid, int* __restrict__ deid) {
    int e = blockIdx.x * 256 + threadIdx.x;
    if (e >= NT) return;
    int s, d;
    if (e < NE) { s = ei[e]; d = ei[NE + e]; } else { s = d = e - NE; }
    seid[atomicAdd(scur + s, 1)] = e;
    deid[atomicAdd(dcur + d, 1)] = e;
}

// ----------------- input embedding: h(bf16) = prelu(x @ x_emb_W) -------------
__global__ __launch_bounds__(128) void k_embed(const float* __restrict__ x, const float* __restrict__ W,
                                               const float* __restrict__ pg, ushort_t* __restrict__ hb) {
    __shared__ float Ws[DA * EMB];   // 50 KB
    __shared__ float xr[DA];
    int t = threadIdx.x;
    for (int i = t; i < DA * EMB; i += 128) Ws[i] = W[i];
    float p = pg[0];
    __syncthreads();
    for (int n = blockIdx.x; n < NN; n += gridDim.x) {
        if (t < DA) xr[t] = x[(size_t)n * DA + t];
        __syncthreads();
        float acc = 0.f;
        #pragma unroll
        for (int k = 0; k < DA; ++k) acc += xr[k] * Ws[k * EMB + t];
        hb[(size_t)n * EMB + t] = f2bf(prelu_f(acc, p));
        __syncthreads();
    }
}

// ----------------- W prep: Wtg[l][n][k] bf16 = wl_W[l][k][n] -----------------
__global__ void k_prep(const float* __restrict__ wlW, ushort_t* __restrict__ Wtg) {
    int idx = blockIdx.x * 256 + threadIdx.x;   // 4*512*128
    if (idx >= 4 * 512 * 128) return;
    int k = idx & 127;
    int n = (idx >> 7) & 511;
    int l = idx >> 16;
    Wtg[idx] = f2bf(wlW[(size_t)l * 65536 + k * 512 + n]);
}

// ----------------- ee_W prep: bf16 copy, same [l][k][ch] layout --------------
__global__ void k_prep_ee(const float* __restrict__ eeW, ushort_t* __restrict__ eeWb) {
    int idx = blockIdx.x * 256 + threadIdx.x;   // 4*13*512
    if (idx >= 4 * DB * HE) return;
    eeWb[idx] = f2bf(eeW[idx]);
}

// ----------------- per-layer GEMM via MFMA: xw = prelu(h @ Wl + bl) ----------
__global__ __launch_bounds__(256) void k_gemm(const ushort_t* __restrict__ hb, const ushort_t* __restrict__ Wtg,
                                              const float* __restrict__ bl, const float* __restrict__ pa,
                                              ushort_t* __restrict__ xw) {
    __shared__ ushort_t At[64 * 136];    // 17.4 KB
    __shared__ ushort_t Bt[128 * 136];   // 34.8 KB
    int t = threadIdx.x;
    int m0 = blockIdx.x * 64;
    int n0 = blockIdx.y * 128;
    for (int idx = t; idx < 64 * 16; idx += 256) {
        int r = idx >> 4, co = (idx & 15) * 8;
        int gr = m0 + r; if (gr >= NN) gr = 0;
        *(uint4*)&At[r * 136 + co] = *(const uint4*)&hb[(size_t)gr * EMB + co];
    }
    for (int idx = t; idx < 128 * 16; idx += 256) {
        int n = idx >> 4, ko = (idx & 15) * 8;
        *(uint4*)&Bt[n * 136 + ko] = *(const uint4*)&Wtg[(size_t)(n0 + n) * 128 + ko];
    }
    float a = pa[0];
    __syncthreads();

    int wv = t >> 6, lane = t & 63;
    int ml = lane & 15, kq = lane >> 4;
    int n0w = wv * 32;
    floatx4 acc[4][2];
    #pragma unroll
    for (int mt = 0; mt < 4; ++mt)
        #pragma unroll
        for (int nt = 0; nt < 2; ++nt)
            acc[mt][nt] = (floatx4){0.f, 0.f, 0.f, 0.f};

    #pragma unroll
    for (int k0 = 0; k0 < 128; k0 += 32) {
        bf16x8 af[4], bfv[2];
        #pragma unroll
        for (int mt = 0; mt < 4; ++mt) {
            uint4 u = *(const uint4*)&At[(mt * 16 + ml) * 136 + k0 + kq * 8];
            af[mt] = __builtin_bit_cast(bf16x8, u);
        }
        #pragma unroll
        for (int nt = 0; nt < 2; ++nt) {
            uint4 u = *(const uint4*)&Bt[(n0w + nt * 16 + ml) * 136 + k0 + kq * 8];
            bfv[nt] = __builtin_bit_cast(bf16x8, u);
        }
        #pragma unroll
        for (int mt = 0; mt < 4; ++mt)
            #pragma unroll
            for (int nt = 0; nt < 2; ++nt)
                acc[mt][nt] = __builtin_amdgcn_mfma_f32_16x16x32_bf16(af[mt], bfv[nt], acc[mt][nt], 0, 0, 0);
    }
    #pragma unroll
    for (int nt = 0; nt < 2; ++nt) {
        int col = n0 + n0w + nt * 16 + ml;
        float bv = bl[col];
        #pragma unroll
        for (int mt = 0; mt < 4; ++mt) {
            int row = m0 + mt * 16 + kq * 4;
            #pragma unroll
            for (int q = 0; q < 4; ++q) {
                int r = row + q;
                if (r < NN) xw[(size_t)r * HE + col] = f2bf(prelu_f(acc[mt][nt][q] + bv, a));
            }
        }
    }
}

// ----------------- per-node attention dots -----------------------------------
__global__ __launch_bounds__(256) void k_dots(const ushort_t* __restrict__ xw,
                                              const float* __restrict__ attl,
                                              float* __restrict__ ddst, float* __restrict__ dsrc) {
    int t = threadIdx.x;
    int lane = t & 63;
    int wid = blockIdx.x * 4 + (t >> 6);
    int nw = gridDim.x * 4;
    int hd = lane >> 4;
    int cm = (lane & 15) * 8;
    float a1[8], a2[8];
    #pragma unroll
    for (int q = 0; q < 8; ++q) {
        a1[q] = attl[hd * 256 + cm + q];
        a2[q] = attl[hd * 256 + 128 + cm + q];
    }
    for (int n = wid; n < NN; n += nw) {
        uint4 u = *(const uint4*)&xw[(size_t)n * HE + lane * 8];
        float v[8] = {bflo(u.x), bfhi(u.x), bflo(u.y), bfhi(u.y),
                      bflo(u.z), bfhi(u.z), bflo(u.w), bfhi(u.w)};
        float p1 = 0.f, p2 = 0.f;
        #pragma unroll
        for (int q = 0; q < 8; ++q) { p1 += v[q] * a1[q]; p2 += v[q] * a2[q]; }
        #pragma unroll
        for (int m = 1; m < 16; m <<= 1) {
            p1 += __shfl_xor(p1, m, 64);
            p2 += __shfl_xor(p2, m, 64);
        }
        if ((lane & 15) == 0) {
            ddst[n * 4 + hd] = p1;
            dsrc[n * 4 + hd] = p2;
        }
    }
}

// ----------------- per-edge raw attention logits (W in 52 bf16 VGPRs) --------
__global__ __launch_bounds__(256) void k_edge(const int* __restrict__ ei, const float* __restrict__ ea,
                                              const ushort_t* __restrict__ eeWb, const float* __restrict__ ebl,
                                              const float* __restrict__ attl, const float* __restrict__ pa,
                                              const float* __restrict__ ddst, const float* __restrict__ dsrc,
                                              float* __restrict__ alpha) {
    int t = threadIdx.x;
    float a = pa[0];
    int lane = t & 63;
    int wid = blockIdx.x * 4 + (t >> 6);
    int nw = gridDim.x * 4;
    int hd = lane >> 4;
    int cm = (lane & 15) * 8;
    int c0 = lane * 8;
    // per-lane weight slice: 13 k x 8 channels, packed bf16 (52 VGPRs)
    uint4 wreg[DB];
    #pragma unroll
    for (int k = 0; k < DB; ++k)
        wreg[k] = *(const uint4*)&eeWb[k * HE + c0];
    float a2[8], eb[8];
    #pragma unroll
    for (int q = 0; q < 8; ++q) {
        a2[q] = attl[hd * 256 + 128 + cm + q];
        eb[q] = ebl[c0 + q];
    }
    float pself = 0.f;
    #pragma unroll
    for (int q = 0; q < 8; ++q) pself += prelu_f(eb[q], a) * a2[q];
    for (int e = wid; e < NT; e += nw) {
        int s, d;
        float p;
        if (e < NE) {
            s = ei[e]; d = ei[NE + e];
            float eav[DB];
            #pragma unroll
            for (int k = 0; k < DB; ++k) eav[k] = ea[(size_t)e * DB + k];
            float v[8];
            #pragma unroll
            for (int q = 0; q < 8; ++q) v[q] = eb[q];
            #pragma unroll
            for (int k = 0; k < DB; ++k) {
                v[0] += eav[k] * bflo(wreg[k].x); v[1] += eav[k] * bfhi(wreg[k].x);
                v[2] += eav[k] * bflo(wreg[k].y); v[3] += eav[k] * bfhi(wreg[k].y);
                v[4] += eav[k] * bflo(wreg[k].z); v[5] += eav[k] * bfhi(wreg[k].z);
                v[6] += eav[k] * bflo(wreg[k].w); v[7] += eav[k] * bfhi(wreg[k].w);
            }
            p = 0.f;
            #pragma unroll
            for (int q = 0; q < 8; ++q) p += prelu_f(v[q], a) * a2[q];
        } else {
            s = d = e - NE;
            p = pself;
        }
        #pragma unroll
        for (int m = 1; m < 16; m <<= 1) p += __shfl_xor(p, m, 64);
        if ((lane & 15) == 0) {
            float di = ddst[d * 4 + hd];
            float sj = dsrc[s * 4 + hd];
            alpha[e * 4 + hd] = prelu_f(di + sj + p, a);
        }
    }
}

// ----------------- segment softmax over src groups ---------------------------
__global__ void k_softmax(const int* __restrict__ soff, const int* __restrict__ seid,
                          float4* __restrict__ alpha) {
    int n = blockIdx.x * 256 + threadIdx.x;
    if (n >= NN) return;
    int b = soff[n], e = soff[n + 1];
    float mx = -1e30f, my = -1e30f, mz = -1e30f, mw = -1e30f;
    for (int i = b; i < e; ++i) {
        float4 v = alpha[seid[i]];
        mx = fmaxf(mx, v.x); my = fmaxf(my, v.y);
        mz = fmaxf(mz, v.z); mw = fmaxf(mw, v.w);
    }
    float sx = 0.f, sy = 0.f, sz = 0.f, sw = 0.f;
    for (int i = b; i < e; ++i) {
        int id = seid[i];
        float4 v = alpha[id];
        v.x = __expf(v.x - mx); v.y = __expf(v.y - my);
        v.z = __expf(v.z - mz); v.w = __expf(v.w - mw);
        sx += v.x; sy += v.y; sz += v.z; sw += v.w;
        alpha[id] = v;
    }
    sx = 1.f / (sx + 1e-16f); sy = 1.f / (sy + 1e-16f);
    sz = 1.f / (sz + 1e-16f); sw = 1.f / (sw + 1e-16f);
    for (int i = b; i < e; ++i) {
        int id = seid[i];
        float4 v = alpha[id];
        v.x *= sx; v.y *= sy; v.z *= sz; v.w *= sw;
        alpha[id] = v;
    }
}

// ----------------- aggregation + head-mean + bias + LayerNorm (+PReLU) -------
// W slice in 52 bf16 VGPRs, no LDS. 2-stage pipeline for the xw gather chain.
__global__ __launch_bounds__(256) void k_aggr(const int* __restrict__ ei, const float* __restrict__ ea,
                                              const ushort_t* __restrict__ eeWb, const float* __restrict__ ebl,
                                              const float* __restrict__ pa, const ushort_t* __restrict__ xw,
                                              const float* __restrict__ alpha,
                                              const int* __restrict__ doff, const int* __restrict__ deid,
                                              const float* __restrict__ gbias, const float* __restrict__ lng,
                                              const float* __restrict__ lnb, const float* __restrict__ pgnn,
                                              int last, ushort_t* __restrict__ hb_out, float* __restrict__ fout) {
    int t = threadIdx.x;
    float a = pa[0], pg = pgnn[0];
    int lane = t & 63;
    int wid = blockIdx.x * 4 + (t >> 6);
    int nw = gridDim.x * 4;
    int hd = lane >> 4;
    int cm = (lane & 15) * 8;
    int c0 = lane * 8;
    uint4 wreg[DB];
    #pragma unroll
    for (int k = 0; k < DB; ++k)
        wreg[k] = *(const uint4*)&eeWb[k * HE + c0];
    float eb[8], ebp[8], gb[8], g[8], bb[8];
    #pragma unroll
    for (int q = 0; q < 8; ++q) {
        eb[q] = ebl[c0 + q];
        ebp[q] = prelu_f(eb[q], a);
        gb[q] = gbias[cm + q];
        g[q] = lng[cm + q];
        bb[q] = lnb[cm + q];
    }
    for (int n = wid; n < NN; n += nw) {
        float acc[8] = {0.f, 0.f, 0.f, 0.f, 0.f, 0.f, 0.f, 0.f};
        int b0 = doff[n], b1 = doff[n + 1];
        int eidA = deid[b0];
        float4 alA = *(const float4*)&alpha[eidA * 4];
        bool intA = eidA < NE;
        int sA;
        float eA[DB];
        if (intA) {
            sA = ei[eidA];
            #pragma unroll
            for (int k = 0; k < DB; ++k) eA[k] = ea[(size_t)eidA * DB + k];
        } else sA = eidA - NE;
        uint4 uA = *(const uint4*)&xw[(size_t)sA * HE + c0];
        for (int i = b0; i < b1; ++i) {
            int eidB = 0, sB = 0;
            float4 alB = alA;
            bool intB = false, haveB = (i + 1 < b1);
            float eB[DB];
            uint4 uB = uA;
            if (haveB) {
                eidB = deid[i + 1];
                alB = *(const float4*)&alpha[eidB * 4];
                intB = eidB < NE;
                if (intB) {
                    sB = ei[eidB];
                    #pragma unroll
                    for (int k = 0; k < DB; ++k) eB[k] = ea[(size_t)eidB * DB + k];
                } else sB = eidB - NE;
                uB = *(const uint4*)&xw[(size_t)sB * HE + c0];
            }
            float alv = hd == 0 ? alA.x : hd == 1 ? alA.y : hd == 2 ? alA.z : alA.w;
            float wv[8];
            if (intA) {
                #pragma unroll
                for (int q = 0; q < 8; ++q) wv[q] = eb[q];
                #pragma unroll
                for (int k = 0; k < DB; ++k) {
                    wv[0] += eA[k] * bflo(wreg[k].x); wv[1] += eA[k] * bfhi(wreg[k].x);
                    wv[2] += eA[k] * bflo(wreg[k].y); wv[3] += eA[k] * bfhi(wreg[k].y);
                    wv[4] += eA[k] * bflo(wreg[k].z); wv[5] += eA[k] * bfhi(wreg[k].z);
                    wv[6] += eA[k] * bflo(wreg[k].w); wv[7] += eA[k] * bfhi(wreg[k].w);
                }
                #pragma unroll
                for (int q = 0; q < 8; ++q) wv[q] = prelu_f(wv[q], a);
            } else {
                #pragma unroll
                for (int q = 0; q < 8; ++q) wv[q] = ebp[q];
            }
            float xv[8] = {bflo(uA.x), bfhi(uA.x), bflo(uA.y), bfhi(uA.y),
                           bflo(uA.z), bfhi(uA.z), bflo(uA.w), bfhi(uA.w)};
            #pragma unroll
            for (int q = 0; q < 8; ++q) acc[q] += (xv[q] + wv[q]) * alv;
            eidA = eidB; alA = alB; intA = intB; sA = sB; uA = uB;
            #pragma unroll
            for (int k = 0; k < DB; ++k) eA[k] = eB[k];
        }
        float hm[8];
        #pragma unroll
        for (int q = 0; q < 8; ++q) {
            float v = acc[q];
            v += __shfl_xor(v, 16, 64);
            v += __shfl_xor(v, 32, 64);
            hm[q] = 0.25f * v + gb[q];
        }
        float s8 = 0.f, q8 = 0.f;
        #pragma unroll
        for (int q = 0; q < 8; ++q) { s8 += hm[q]; q8 += hm[q] * hm[q]; }
        #pragma unroll
        for (int m = 1; m < 16; m <<= 1) {
            s8 += __shfl_xor(s8, m, 64);
            q8 += __shfl_xor(q8, m, 64);
        }
        float mu = s8 * (1.f / 128.f);
        float var = q8 * (1.f / 128.f) - mu * mu;
        float rstd = rsqrtf(var + 1e-5f);
        if (lane < 16) {
            float o[8];
            #pragma unroll
            for (int q = 0; q < 8; ++q) {
                float v = (hm[q] - mu) * rstd * g[q] + bb[q];
                o[q] = last ? v : prelu_f(v, pg);
            }
            if (last) {
                float4* op = (float4*)&fout[(size_t)n * EMB + lane * 8];
                op[0] = make_float4(o[0], o[1], o[2], o[3]);
                op[1] = make_float4(o[4], o[5], o[6], o[7]);
            } else {
                uint4 ob;
                ob.x = (unsigned)f2bf(o[0]) | ((unsigned)f2bf(o[1]) << 16);
                ob.y = (unsigned)f2bf(o[2]) | ((unsigned)f2bf(o[3]) << 16);
                ob.z = (unsigned)f2bf(o[4]) | ((unsigned)f2bf(o[5]) << 16);
                ob.w = (unsigned)f2bf(o[6]) | ((unsigned)f2bf(o[7]) << 16);
                *(uint4*)&hb_out[(size_t)n * EMB + lane * 8] = ob;
            }
        }
    }
}

extern "C" void kernel_launch(void* const* d_in, const int* in_sizes, int n_in,
                              void* d_out, int out_size, void* d_ws, size_t ws_size,
                              hipStream_t stream) {
    const float* x     = (const float*)d_in[0];
    const int*   ei    = (const int*)d_in[1];      // int32 (JAX x64 disabled)
    const float* ea    = (const float*)d_in[2];
    const float* xembW = (const float*)d_in[3];
    const float* pgnn  = (const float*)d_in[4];
    const float* wlW   = (const float*)d_in[5];
    const float* wlb   = (const float*)d_in[6];
    const float* att   = (const float*)d_in[7];
    const float* gbias = (const float*)d_in[8];
    const float* eeW   = (const float*)d_in[9];
    const float* eeb   = (const float*)d_in[10];
    const float* pgat  = (const float*)d_in[11];
    const float* lng   = (const float*)d_in[12];
    const float* lnb   = (const float*)d_in[13];

    char* w = (char*)d_ws;
    size_t off = 0;
    auto alloc = [&](size_t nbytes) -> char* {
        char* p = w + off;
        off += (nbytes + 255) & ~(size_t)255;
        return p;
    };
    ushort_t* hb    = (ushort_t*)alloc((size_t)NN * EMB * 2);   // 25.6 MB bf16
    ushort_t* xw    = (ushort_t*)alloc((size_t)NN * HE * 2);    // 102.4 MB bf16
    ushort_t* Wtg   = (ushort_t*)alloc((size_t)4 * 512 * 128 * 2);
    ushort_t* eeWb  = (ushort_t*)alloc((size_t)4 * DB * HE * 2);
    float*    ddst  = (float*)alloc((size_t)NN * 4 * 4);
    float*    dsrc  = (float*)alloc((size_t)NN * 4 * 4);
    float*    alpha = (float*)alloc((size_t)NT * 4 * 4);        // 8 MB
    int* scnt = (int*)alloc((size_t)NN * 4);
    int* dcnt = (int*)alloc((size_t)NN * 4);
    int* soff = (int*)alloc((size_t)(NN + 1) * 4);
    int* doff = (int*)alloc((size_t)(NN + 1) * 4);
    int* scur = (int*)alloc((size_t)NN * 4);
    int* dcur = (int*)alloc((size_t)NN * 4);
    int* seid = (int*)alloc((size_t)NT * 4);
    int* deid = (int*)alloc((size_t)NT * 4);
    int* part = (int*)alloc((size_t)NN * 4);
    int* bsum = (int*)alloc(256 * 4);

    hipMemsetAsync(scnt, 0, (size_t)NN * 4, stream);
    hipMemsetAsync(dcnt, 0, (size_t)NN * 4, stream);
    k_count<<<(NT + 255) / 256, 256, 0, stream>>>(ei, scnt, dcnt);
    k_scan1<<<196, 512, 0, stream>>>(scnt, part, bsum);
    k_scan2<<<1, 256, 0, stream>>>(bsum, 196);
    k_scan3<<<391, 256, 0, stream>>>(part, bsum, soff, scur);
    k_scan1<<<196, 512, 0, stream>>>(dcnt, part, bsum);
    k_scan2<<<1, 256, 0, stream>>>(bsum, 196);
    k_scan3<<<391, 256, 0, stream>>>(part, bsum, doff, dcur);
    k_fill<<<(NT + 255) / 256, 256, 0, stream>>>(ei, scur, dcur, seid, deid);
    k_embed<<<2048, 128, 0, stream>>>(x, xembW, pgnn, hb);
    k_prep<<<(4 * 512 * 128 + 255) / 256, 256, 0, stream>>>(wlW, Wtg);
    k_prep_ee<<<(4 * DB * HE + 255) / 256, 256, 0, stream>>>(eeW, eeWb);

    for (int l = 0; l < 4; ++l) {
        const float* bl  = wlb + (size_t)l * HE;
        const float* al  = att + (size_t)l * 1024;
        const ushort_t* eWl = eeWb + (size_t)l * DB * HE;
        const float* ebl = eeb + (size_t)l * HE;
        const float* pa  = pgat + l;
        const ushort_t* Wt = Wtg + (size_t)l * 512 * 128;
        k_gemm<<<dim3((NN + 63) / 64, 4), 256, 0, stream>>>(hb, Wt, bl, pa, xw);
        k_dots<<<2048, 256, 0, stream>>>(xw, al, ddst, dsrc);
        k_edge<<<2048, 256, 0, stream>>>(ei, ea, eWl, ebl, al, pa, ddst, dsrc, alpha);
        k_softmax<<<391, 256, 0, stream>>>(soff, seid, (float4*)alpha);
        k_aggr<<<2048, 256, 0, stream>>>(ei, ea, eWl, ebl, pa, xw, alpha, doff, deid,
                                         gbias + (size_t)l * EMB, lng + (size_t)l * EMB,
                                         lnb + (size_t)l * EMB, pgnn, (l == 3) ? 1 : 0,
                                         hb, (float*)d_out);
    }
}